// Round 4
// baseline (834.488 us; speedup 1.0000x reference)
//
#include <hip/hip_runtime.h>

// LSTM: SEQ=4096, BATCH=4096, IN=2, HID=8, fp32.
// R10 = all-gates-local. 8 lanes/batch: lane u owns ALL FOUR gate rows of
// unit u -> i,f,g~,o computed in-lane; c = f*c + i*g~ and h fully local.
// ZERO gate-exchange ops (R9 still had 3 ror8 DPPs + half-duplicated work).
// Only cross-lane op: the h-gather, 7 DPPs per wave-step.
// Packed split-dot: P_m = (h_{u^m}, h_{u^m^7}) pairs (1 HMIR + 3 pair
// quad-perms), each 8-term row dot = 1 pk_fma (x,bias init) + 4 pk_fma +
// 1 combine add. 8 batches/wave, 512 waves (half the SIMDs idle -- fine:
// the kernel is latency-bound; only cycles/step matter).
// Numerics identical to R6-R9: rows pre-scaled by -log2e (-2log2e for g~),
// c kept in scaled space c' = -2*log2e*c, sigmoid/tanh via exp2+rcp only.

#define SEQ   4096
#define BATCH 4096
#define PF    8

#define DPP_X1   0xB1  // quad_perm [1,0,3,2] : lane ^ 1
#define DPP_X2   0x4E  // quad_perm [2,3,0,1] : lane ^ 2
#define DPP_X3   0x1B  // quad_perm [3,2,1,0] : lane ^ 3
#define DPP_HMIR 0x141 // row_half_mirror     : lane ^ 7 (within 8-lane half)

typedef float v2f __attribute__((ext_vector_type(2)));

template<int CTRL>
__device__ __forceinline__ float rot(float v) {
    int i = __builtin_bit_cast(int, v);
    int r = __builtin_amdgcn_update_dpp(0, i, CTRL, 0xf, 0xf, true);
    return __builtin_bit_cast(float, r);
}
template<int CTRL>
__device__ __forceinline__ v2f dpp2(v2f v) {
    v2f r; r.x = rot<CTRL>(v.x); r.y = rot<CTRL>(v.y); return r;
}
__device__ __forceinline__ v2f vfma(v2f a, v2f b, v2f c) {
    return __builtin_elementwise_fma(a, b, c);
}

__global__ __launch_bounds__(64, 1) void lstm_kernel(
    const float* __restrict__ x,    // (SEQ, BATCH, 2)
    const float* __restrict__ h0,   // (1, BATCH, 8)
    const float* __restrict__ c0,   // (1, BATCH, 8)
    const float* __restrict__ Wih,  // (32, 2)
    const float* __restrict__ Whh,  // (32, 8)
    const float* __restrict__ bih,  // (32)
    const float* __restrict__ bhh,  // (32)
    float* __restrict__ out)        // (1, BATCH, 8)
{
    const int tid = threadIdx.x;
    const int u   = tid & 7;                    // unit 0..7
    const int b   = blockIdx.x * 8 + (tid >> 3);

    const float L2E = 1.4426950408889634f;
    const float nL  = -L2E;
    const float n2L = -2.0f * L2E;

    // gate rows of unit u (PyTorch order): i=u, f=8+u, g~=16+u, o=24+u
    const int ri = u, rf = 8 + u, rg = 16 + u, ro = 24 + u;

    // Whh in split-gather order: pair m covers columns (u^m, u^m^7); the four
    // m's lo-halves cover u's quad, hi-halves the mirror quad = all 8 cols.
    v2f Wi[4], Wf[4], Wg[4], Wo[4];
#pragma unroll
    for (int m = 0; m < 4; ++m) {
        const int ka = u ^ m, kb = ka ^ 7;
        Wi[m] = (v2f){ Whh[ri * 8 + ka], Whh[ri * 8 + kb] } * nL;
        Wf[m] = (v2f){ Whh[rf * 8 + ka], Whh[rf * 8 + kb] } * nL;
        Wg[m] = (v2f){ Whh[rg * 8 + ka], Whh[rg * 8 + kb] } * n2L;
        Wo[m] = (v2f){ Whh[ro * 8 + ka], Whh[ro * 8 + kb] } * nL;
    }
    const v2f WXi = (v2f){ Wih[2 * ri], Wih[2 * ri + 1] } * nL;
    const v2f WXf = (v2f){ Wih[2 * rf], Wih[2 * rf + 1] } * nL;
    const v2f WXg = (v2f){ Wih[2 * rg], Wih[2 * rg + 1] } * n2L;
    const v2f WXo = (v2f){ Wih[2 * ro], Wih[2 * ro + 1] } * nL;
    const v2f Bi = { (bih[ri] + bhh[ri]) * nL,  0.0f };
    const v2f Bf = { (bih[rf] + bhh[rf]) * nL,  0.0f };
    const v2f Bg = { (bih[rg] + bhh[rg]) * n2L, 0.0f };
    const v2f Bo = { (bih[ro] + bhh[ro]) * nL,  0.0f };

    // state: c in scaled space c' = -2*L2E*c; h = h_u, one unit per lane
    float c = c0[b * 8 + u] * n2L;
    float h = h0[b * 8 + u];

    const float2* __restrict__ xp2 = (const float2*)x;
    float2 xb[PF];
#pragma unroll
    for (int p = 0; p < PF; ++p) xb[p] = xp2[p * BATCH + b];

    for (int s = 0; s < SEQ; s += PF) {
#pragma unroll
        for (int p = 0; p < PF; ++p) {
            const float2 xc = xb[p];
            const int sn = (s + p + PF) & (SEQ - 1);   // uniform wrap
            xb[p] = xp2[sn * BATCH + b];
            const v2f xv = { xc.x, xc.y };

            // ---- h-gather: P_m = (h_{u^m}, h_{u^m^7}); 7 DPPs total
            v2f P0; P0.x = h; P0.y = rot<DPP_HMIR>(h);
            const v2f P1 = dpp2<DPP_X1>(P0);
            const v2f P2 = dpp2<DPP_X2>(P0);
            const v2f P3 = dpp2<DPP_X3>(P0);

            // ---- four packed split-dots (independent chains, depth 6)
            v2f ai = vfma(xv, WXi, Bi);
            v2f af = vfma(xv, WXf, Bf);
            v2f ag = vfma(xv, WXg, Bg);
            v2f ao = vfma(xv, WXo, Bo);
            ai = vfma(P0, Wi[0], ai);  af = vfma(P0, Wf[0], af);
            ag = vfma(P0, Wg[0], ag);  ao = vfma(P0, Wo[0], ao);
            ai = vfma(P1, Wi[1], ai);  af = vfma(P1, Wf[1], af);
            ag = vfma(P1, Wg[1], ag);  ao = vfma(P1, Wo[1], ao);
            ai = vfma(P2, Wi[2], ai);  af = vfma(P2, Wf[2], af);
            ag = vfma(P2, Wg[2], ag);  ao = vfma(P2, Wo[2], ao);
            ai = vfma(P3, Wi[3], ai);  af = vfma(P3, Wf[3], af);
            ag = vfma(P3, Wg[3], ag);  ao = vfma(P3, Wo[3], ao);
            const float pi = ai.x + ai.y;   // already scaled by -L2E
            const float pf = af.x + af.y;
            const float pg = ag.x + ag.y;   // scaled by -2*L2E
            const float po = ao.x + ao.y;

            // ---- activations, all in-lane (4 independent trans chains)
            const float e_i = __builtin_amdgcn_exp2f(pi);
            const float e_f = __builtin_amdgcn_exp2f(pf);
            const float e_g = __builtin_amdgcn_exp2f(pg);
            const float e_o = __builtin_amdgcn_exp2f(po);
            const float r_i = __builtin_amdgcn_rcpf(e_i + 1.0f);
            const float r_f = __builtin_amdgcn_rcpf(e_f + 1.0f);
            const float r_g = __builtin_amdgcn_rcpf(e_g + 1.0f);
            const float r_o = __builtin_amdgcn_rcpf(e_o + 1.0f);
            const float gi  = r_i * n2L;                        // -2L2E*sig_i
            const float gg  = __builtin_fmaf(r_g, 2.0f, -1.0f); // tanh(g~)
            const float go2 = r_o + r_o;                        // 2*sig_o

            // ---- c/h update, fully local (no cross-lane ops at all)
            c = __builtin_fmaf(r_f, c, gi * gg);       // scaled-c recurrence
            const float e2 = __builtin_amdgcn_exp2f(c);
            const float r2 = __builtin_amdgcn_rcpf(e2 + 1.0f);
            h = __builtin_fmaf(go2, r2, go2 * -0.5f);  // h = 2sig*r - sig
        }
    }

    out[b * 8 + u] = h;   // every lane writes its own unit; fully coalesced
}

extern "C" void kernel_launch(void* const* d_in, const int* in_sizes, int n_in,
                              void* d_out, int out_size, void* d_ws, size_t ws_size,
                              hipStream_t stream) {
    const float* x   = (const float*)d_in[0];
    const float* h0  = (const float*)d_in[1];
    const float* c0  = (const float*)d_in[2];
    const float* Wih = (const float*)d_in[3];
    const float* Whh = (const float*)d_in[4];
    const float* bih = (const float*)d_in[5];
    const float* bhh = (const float*)d_in[6];
    float* out = (float*)d_out;

    dim3 grid(BATCH / 8);    // 512 single-wave blocks -> 2 waves/CU
    dim3 block(64);          // 1 wave = 8 batches x 8 lanes
    hipLaunchKernelGGL(lstm_kernel, grid, block, 0, stream,
                       x, h0, c0, Wih, Whh, bih, bhh, out);
}